// Round 22
// baseline (152.227 us; speedup 1.0000x reference)
//
#include <hip/hip_runtime.h>
#include <hip/hip_bf16.h>

// B=4, S=4096, D=512, FH=2048, H=64
// outputs: progress (B*S) ++ forecast (B*S) ++ fore (B*S*D), all f32
//
// Structure (7 launches):
//   L1 convA: W2b/W1t/Wihb bf16 + gxbias                  (~4us)
//   L2 convB: Weffb/WeffTb tiles (front, latency-bound) overlapped with
//             xb conversion stream + beff                  (~14us)
//   L3 wggx:  Wgb tiles + bf2 + Gx tiles                   (~8us)
//   K1: scan-A0 + 1024 fore tiles (XCD-swizzled, wg-free)  (~40us)
//   K2: scan-B0 + 128 Gf tiles
//   K3: scan-A1
//   K4: scan-B1 with FUSED forecast cells + output broadcasts

#if __has_builtin(__builtin_amdgcn_exp2f)
__device__ __forceinline__ float EXP2(float x) { return __builtin_amdgcn_exp2f(x); }
#else
__device__ __forceinline__ float EXP2(float x) { return __expf(x * 0.6931471805599453f); }
#endif
#if __has_builtin(__builtin_amdgcn_rcpf)
__device__ __forceinline__ float RCPF(float x) { return __builtin_amdgcn_rcpf(x); }
#else
__device__ __forceinline__ float RCPF(float x) { return 1.0f / x; }
#endif

constexpr float L2E  = 1.4426950408889634f;
constexpr float L2E2 = 2.8853900817779268f;

__device__ __forceinline__ float sig_f(float x)  { return RCPF(1.0f + EXP2(-L2E * x)); }
__device__ __forceinline__ float tanh_f(float x) { return fmaf(-2.0f, RCPF(1.0f + EXP2(L2E2 * x)), 1.0f); }

template<int CTRL>
__device__ __forceinline__ float dppadd(float x) {
    return x + __int_as_float(__builtin_amdgcn_update_dpp(
        0, __float_as_int(x), CTRL, 0xf, 0xf, true));
}
__device__ __forceinline__ float dpp_sum64_lane63(float x) {
    x = dppadd<0x111>(x); x = dppadd<0x112>(x); x = dppadd<0x114>(x);
    x = dppadd<0x118>(x); x = dppadd<0x142>(x); x = dppadd<0x143>(x);
    return x;
}
__device__ __forceinline__ float readlane63(float x) {
    return __int_as_float(__builtin_amdgcn_readlane(__float_as_int(x), 63));
}
__device__ __forceinline__ float readlane_s(float x, int s) {
    return __int_as_float(__builtin_amdgcn_readlane(__float_as_int(x), s));
}

using bf16x8 = __attribute__((ext_vector_type(8))) __bf16;
using f32x4  = __attribute__((ext_vector_type(4))) float;

// ---------------------------------------------------------------------------
// MFMA 128x64 tile with LDS-staged B panel (64x512 bf16 = 64KB, XOR-swizzled).
// A: [M][lda] bf16 row-major (k-contiguous), VMEM double-buffered.
// B: [N][ldb] bf16 (B^T layout); staged per 512-k chunk into Bs.
// mfma_f32_16x16x32_bf16 layouts (verified round 11):
//   A/B-frag lane l: row/col = l&15, k = (l>>4)*8 + j
//   D        lane l: col = l&15, row = (l>>4)*4 + i
// ---------------------------------------------------------------------------
__device__ __forceinline__ void mfma_tile128_lds(
    const __hip_bfloat16* __restrict__ A, int lda,
    const __hip_bfloat16* __restrict__ B, int ldb,
    int K, int bm, int bn,
    const float* __restrict__ bias,                 // nullptr -> none
    float* __restrict__ Cf, int ldc,                // nullptr -> skip
    __hip_bfloat16* __restrict__ Cb,                // nullptr -> skip (ldc)
    __hip_bfloat16* __restrict__ Ct, int ldt,       // nullptr -> skip (transposed)
    __hip_bfloat16* __restrict__ Bs)                // shared, 64*512 elems
{
    const int tid  = threadIdx.x;
    const int w    = tid >> 6;
    const int lane = tid & 63;
    const int rc   = lane & 15;
    const int kg   = lane >> 4;
    const __hip_bfloat16* ap0 = A + (size_t)(bm + w * 16 + rc) * lda + kg * 8;
    const __hip_bfloat16* ap1 = ap0 + (size_t)64 * lda;

#define LD8(P) (*reinterpret_cast<const bf16x8*>(P))
    const f32x4 z{0.f, 0.f, 0.f, 0.f};
    f32x4 c00 = z, c01 = z, c02 = z, c03 = z;
    f32x4 c10 = z, c11 = z, c12 = z, c13 = z;

    for (int kb = 0; kb < K; kb += 512) {
        __syncthreads();
        #pragma unroll
        for (int i = 0; i < 16; ++i) {
            const int G = i * 256 + tid;
            const int row = G >> 6, kc = G & 63;
            const bf16x8 v = LD8(B + (size_t)(bn + row) * ldb + kb + kc * 8);
            *reinterpret_cast<bf16x8*>(Bs + row * 512 + ((kc ^ (row & 7)) << 3)) = v;
        }
        __syncthreads();

        bf16x8 a0 = LD8(ap0 + kb), a1 = LD8(ap1 + kb);
        #pragma unroll 4
        for (int s = 0; s < 16; ++s) {
            bf16x8 a0n = a0, a1n = a1;
            if (s < 15) {
                a0n = LD8(ap0 + kb + (s + 1) * 32);
                a1n = LD8(ap1 + kb + (s + 1) * 32);
            }
            bf16x8 bf[4];
            #pragma unroll
            for (int g = 0; g < 4; ++g) {
                const int row = g * 16 + rc;
                const int off = row * 512 + (((s * 4 + kg) ^ (row & 7)) << 3);
                bf[g] = *reinterpret_cast<const bf16x8*>(Bs + off);
            }
            c00 = __builtin_amdgcn_mfma_f32_16x16x32_bf16(a0, bf[0], c00, 0, 0, 0);
            c01 = __builtin_amdgcn_mfma_f32_16x16x32_bf16(a0, bf[1], c01, 0, 0, 0);
            c02 = __builtin_amdgcn_mfma_f32_16x16x32_bf16(a0, bf[2], c02, 0, 0, 0);
            c03 = __builtin_amdgcn_mfma_f32_16x16x32_bf16(a0, bf[3], c03, 0, 0, 0);
            c10 = __builtin_amdgcn_mfma_f32_16x16x32_bf16(a1, bf[0], c10, 0, 0, 0);
            c11 = __builtin_amdgcn_mfma_f32_16x16x32_bf16(a1, bf[1], c11, 0, 0, 0);
            c12 = __builtin_amdgcn_mfma_f32_16x16x32_bf16(a1, bf[2], c12, 0, 0, 0);
            c13 = __builtin_amdgcn_mfma_f32_16x16x32_bf16(a1, bf[3], c13, 0, 0, 0);
            a0 = a0n; a1 = a1n;
        }
    }
#undef LD8

    const int row0 = bm + w * 16 + kg * 4;
    const int colb = bn + rc;
#define EPI(ACC, HOFF, CT) {                                                  \
        const int col = colb + (CT) * 16;                                     \
        const float bb = bias ? bias[col] : 0.0f;                             \
        _Pragma("unroll")                                                     \
        for (int i = 0; i < 4; ++i) {                                         \
            const float v = (ACC)[i] + bb;                                    \
            const int row = row0 + (HOFF) + i;                                \
            if (Cf) Cf[(size_t)row * ldc + col] = v;                          \
            if (Cb) Cb[(size_t)row * ldc + col] = __float2bfloat16(v);        \
            if (Ct) Ct[(size_t)col * ldt + row] = __float2bfloat16(v);        \
        }}
    EPI(c00, 0, 0)  EPI(c01, 0, 1)  EPI(c02, 0, 2)  EPI(c03, 0, 3)
    EPI(c10, 64, 0) EPI(c11, 64, 1) EPI(c12, 64, 2) EPI(c13, 64, 3)
#undef EPI
}

// ---------------------------------------------------------------------------
// L1 convA: [0,1024) W2b | [1024,1280) W1t (LDS transpose) |
//           [1280,1408) Wihb | 1408 gxbias
// ---------------------------------------------------------------------------
__global__ __launch_bounds__(256) void convA_kernel(
    const float* __restrict__ W2, const float* __restrict__ W1,
    const float* __restrict__ Wih,
    const float* __restrict__ bih, const float* __restrict__ bhh,
    __hip_bfloat16* __restrict__ W2b, __hip_bfloat16* __restrict__ W1t,
    __hip_bfloat16* __restrict__ Wihb, float* __restrict__ gxbias)
{
    const int bid = blockIdx.x, tid = threadIdx.x;
#define CVT4(SRC, DST, BASE) {                                                \
        const size_t i = ((size_t)(BASE) * 256 + tid) * 4;                    \
        const float4 v = *reinterpret_cast<const float4*>((SRC) + i);         \
        __hip_bfloat16 o[4] = {__float2bfloat16(v.x), __float2bfloat16(v.y),  \
                               __float2bfloat16(v.z), __float2bfloat16(v.w)}; \
        *reinterpret_cast<ushort4*>((DST) + i) =                              \
            *reinterpret_cast<const ushort4*>(o); }
    if (bid < 1024) {
        CVT4(W2, W2b, bid)
    } else if (bid < 1280) {
        __shared__ float lds[64][65];
        const int b = bid - 1024;
        const int br = b >> 3, bc = b & 7;
        const int r0 = tid >> 4, c4 = (tid & 15) * 4;
        #pragma unroll
        for (int u = 0; u < 4; ++u) {
            const int row = r0 + u * 16;
            const float4 v = *reinterpret_cast<const float4*>(
                &W1[(size_t)(br * 64 + row) * 512 + bc * 64 + c4]);
            lds[row][c4 + 0] = v.x; lds[row][c4 + 1] = v.y;
            lds[row][c4 + 2] = v.z; lds[row][c4 + 3] = v.w;
        }
        __syncthreads();
        const int jj0 = tid >> 4, kk4 = (tid & 15) * 4;
        #pragma unroll
        for (int u = 0; u < 4; ++u) {
            const int jj = jj0 + u * 16;
            __hip_bfloat16 o[4] = {
                __float2bfloat16(lds[kk4 + 0][jj]), __float2bfloat16(lds[kk4 + 1][jj]),
                __float2bfloat16(lds[kk4 + 2][jj]), __float2bfloat16(lds[kk4 + 3][jj])};
            *reinterpret_cast<ushort4*>(
                &W1t[(size_t)(bc * 64 + jj) * 2048 + br * 64 + kk4]) =
                *reinterpret_cast<const ushort4*>(o);
        }
    } else if (bid < 1408) {
        CVT4(Wih, Wihb, bid - 1280)
    } else {
        gxbias[tid] = bih[tid] + bhh[tid];
    }
#undef CVT4
}

// ---------------------------------------------------------------------------
// L2 convB: [0,32) Weffb/WeffTb tiles (FRONT, overlap xb stream);
//           [32,40) beff f32; [40,2088) xb conversion (ILP-4 per thread)
// ---------------------------------------------------------------------------
__global__ __launch_bounds__(256) void convB_kernel(
    const float* __restrict__ x, const float* __restrict__ W2,
    const float* __restrict__ b1, const float* __restrict__ b2,
    const __hip_bfloat16* __restrict__ W2b, const __hip_bfloat16* __restrict__ W1t,
    __hip_bfloat16* __restrict__ xb,
    __hip_bfloat16* __restrict__ Weffb, __hip_bfloat16* __restrict__ WeffTb,
    float* __restrict__ beff)
{
    __shared__ __hip_bfloat16 Bs[64 * 512];
    const int bid = blockIdx.x, tid = threadIdx.x;
    if (bid < 32) {
        const int bm = (bid >> 3) * 128, bn = (bid & 7) * 64;
        mfma_tile128_lds(W2b, 2048, W1t, 2048, 2048, bm, bn, nullptr,
                         nullptr, 512, Weffb, WeffTb, 512, Bs);
    } else if (bid < 40) {
        const int w = tid >> 6, j = tid & 63;
        const int base = (bid - 32) * 64 + w * 16;
        for (int o = 0; o < 16; ++o) {
            const int i = base + o;
            float s = 0.0f;
            #pragma unroll
            for (int m = 0; m < 32; ++m)
                s = fmaf(W2[(size_t)i * 2048 + j + 64 * m], b1[j + 64 * m], s);
            s = dpp_sum64_lane63(s);
            if (j == 63) beff[i] = s + b2[i];
        }
    } else {
        const int b = bid - 40;                       // 2048 blocks, 1024 f4 each
        const float4* src = reinterpret_cast<const float4*>(x) + (size_t)b * 1024;
        ushort4* dst = reinterpret_cast<ushort4*>(xb) + (size_t)b * 1024;
        float4 v[4];
        #pragma unroll
        for (int u = 0; u < 4; ++u) v[u] = src[u * 256 + tid];
        #pragma unroll
        for (int u = 0; u < 4; ++u) {
            __hip_bfloat16 o[4] = {__float2bfloat16(v[u].x), __float2bfloat16(v[u].y),
                                   __float2bfloat16(v[u].z), __float2bfloat16(v[u].w)};
            dst[u * 256 + tid] = *reinterpret_cast<const ushort4*>(o);
        }
    }
}

// ---------------------------------------------------------------------------
// L3 wggx: [0,16) Wgb = Wihb@WeffT tiles; 16: bf2 = Wih@beff;
//          [17,145) Gx = xb@Wihb^T + gxbias (identity map)
// ---------------------------------------------------------------------------
__global__ __launch_bounds__(256) void wggx_kernel(
    const __hip_bfloat16* __restrict__ Wihb, const __hip_bfloat16* __restrict__ WeffTb,
    const __hip_bfloat16* __restrict__ xb,
    const float* __restrict__ Wih, const float* __restrict__ beff,
    const float* __restrict__ gxbias,
    __hip_bfloat16* __restrict__ Wgb, float* __restrict__ bf2,
    float* __restrict__ Gx)
{
    __shared__ __hip_bfloat16 Bs[64 * 512];
    const int bid = blockIdx.x;
    if (bid < 16) {
        const int bm = (bid >> 3) * 128, bn = (bid & 7) * 64;
        mfma_tile128_lds(Wihb, 512, WeffTb, 512, 512, bm, bn, nullptr,
                         nullptr, 512, Wgb, nullptr, 0, Bs);
    } else if (bid == 16) {
        const int w = threadIdx.x >> 6, j = threadIdx.x & 63;
        for (int o = 0; o < 64; ++o) {
            const int i = w * 64 + o;
            float s = 0.0f;
            #pragma unroll
            for (int m = 0; m < 8; ++m)
                s = fmaf(Wih[(size_t)i * 512 + j + 64 * m], beff[j + 64 * m], s);
            s = dpp_sum64_lane63(s);
            if (j == 63) bf2[i] = s;
        }
    } else {
        const int b = bid - 17;                       // 128 Gx tiles
        const int bm = (b >> 2) * 128, bn = (b & 3) * 64;
        mfma_tile128_lds(xb, 512, Wihb, 512, 512, bm, bn, gxbias,
                         Gx, 256, nullptr, nullptr, 0, Bs);
    }
}

// ---------------------------------------------------------------------------
// fused: [0,32) scan phase (128 chunk-waves, CH=32);
//        [32,32+fore_cnt) fore tiles (XCD-swizzled); then gf_cnt Gf tiles.
// phase B + last: forecast cell fused; outputs written directly.
// ---------------------------------------------------------------------------
__global__ __launch_bounds__(256) void fused_kernel(
    int phase, int first, int last,
    int fore_cnt, int gf_cnt,
    const __hip_bfloat16* __restrict__ xb, const __hip_bfloat16* __restrict__ Weffb,
    const __hip_bfloat16* __restrict__ Wgb_in,
    const float* __restrict__ beff, const float* __restrict__ bf2,
    const float* __restrict__ Gx, float* __restrict__ Gf,
    const float* __restrict__ Gf_in, const float* __restrict__ gxbias,
    const float* __restrict__ Whh, const float* __restrict__ Whr,
    const float* __restrict__ hprev, float* __restrict__ hnext,
    float* __restrict__ P, float* __restrict__ Q,
    float* __restrict__ fore, float* __restrict__ out)
{
    __shared__ __hip_bfloat16 Bs[64 * 512];
    constexpr int CH = 32;                          // steps per chunk
    constexpr int S = 4096, BS = 4 * 4096;

    if (blockIdx.x < 32) {
        const int chunk = blockIdx.x * 4 + (threadIdx.x >> 6);  // 0..127
        const int j = threadIdx.x & 63;
        const float wi = Whh[j], wf = Whh[64 + j];
        const float wg2 = Whh[128 + j], wo = Whh[192 + j];
        const float* ab = Gx + (size_t)chunk * CH * 256 + j;

        float hp = 0.0f;
        if (!first) {
            const int idx = chunk * CH - 1 + j;
            hp = (idx >= 0 && idx < S) ? hprev[idx] : 0.0f;
        }

        if (phase == 0) {
            float Pv = 1.0f, Qv = 0.0f;
            #pragma unroll 8
            for (int s = 0; s < CH; ++s) {
                const float hs = first ? 0.0f : readlane_s(hp, s);
                const float ai = ab[s * 256]       + wi  * hs;
                const float af = ab[s * 256 + 64]  + wf  * hs;
                const float ag = ab[s * 256 + 128] + wg2 * hs;
                const float si = sig_f(ai);
                const float sf = sig_f(af);
                const float tg = tanh_f(ag);
                Pv = sf * Pv;
                Qv = fmaf(sf, Qv, si * tg);
            }
            P[chunk * 64 + j] = Pv;
            Q[chunk * 64 + j] = Qv;
        } else {
            const float whr = Whr[j];
            float c = 0.0f;
            #pragma unroll 8
            for (int m = 0; m < chunk; ++m)
                c = fmaf(P[m * 64 + j], c, Q[m * 64 + j]);
            float vp = 0.0f, vpf = 0.0f;
            const float* gfp = Gf_in ? Gf_in + (size_t)chunk * CH * 256 + j : nullptr;
            const float bi0 = gxbias[j],        bi1 = gxbias[64 + j];
            const float bi2 = gxbias[128 + j],  bi3 = gxbias[192 + j];
            #pragma unroll 4
            for (int s = 0; s < CH; ++s) {
                const float hs = first ? 0.0f : readlane_s(hp, s);
                const float ai = ab[s * 256]       + wi  * hs;
                const float af = ab[s * 256 + 64]  + wf  * hs;
                const float ag = ab[s * 256 + 128] + wg2 * hs;
                const float ao = ab[s * 256 + 192] + wo  * hs;
                const float si = sig_f(ai);
                const float sf = sig_f(af);
                const float tg = tanh_f(ag);
                const float so = sig_f(ao);
                c = fmaf(sf, c, si * tg);
                const float tc = tanh_f(c);
                float hv = tc * (so * whr);
                hv = dpp_sum64_lane63(hv);
                const float hn = readlane63(hv);
                vp = (j == s) ? hn : vp;
                if (last) {
                    const float fi = gfp[s * 256]       + bi0 + wi  * hn;
                    const float ff = gfp[s * 256 + 64]  + bi1 + wf  * hn;
                    const float fg = gfp[s * 256 + 128] + bi2 + wg2 * hn;
                    const float fo = gfp[s * 256 + 192] + bi3 + wo  * hn;
                    const float cf = sig_f(ff) * c + sig_f(fi) * tanh_f(fg);
                    float hf = sig_f(fo) * tanh_f(cf) * whr;
                    hf = dpp_sum64_lane63(hf);
                    const float hfn = readlane63(hf);
                    vpf = (j == s) ? hfn : vpf;
                }
            }
            if (j < CH) {
                const int t = chunk * CH + j;
                if (last) {
                    #pragma unroll
                    for (int b = 0; b < 4; ++b) {
                        out[b * S + t]      = vp;
                        out[BS + b * S + t] = vpf;
                    }
                } else {
                    hnext[t] = vp;
                }
            }
        }
        return;
    }

    const int bt = blockIdx.x - 32;
    if (bt < fore_cnt) {                   // fore: 1024 tiles, XCD-swizzled
        const int tile = (bt & 7) * 128 + (bt >> 3);   // stride-8 peers share panel
        const int bm = (tile >> 3) * 128, bn = (tile & 7) * 64;
        mfma_tile128_lds(xb, 512, Weffb, 512, 512, bm, bn, beff,
                         fore, 512, nullptr, nullptr, 0, Bs);
    } else if (bt < fore_cnt + gf_cnt) {   // Gf: 128 tiles, identity
        const int g = bt - fore_cnt;
        const int bm = (g >> 2) * 128, bn = (g & 3) * 64;
        mfma_tile128_lds(xb, 512, Wgb_in, 512, 512, bm, bn, bf2,
                         Gf, 256, nullptr, nullptr, 0, Bs);
    }
}

extern "C" void kernel_launch(void* const* d_in, const int* in_sizes, int n_in,
                              void* d_out, int out_size, void* d_ws, size_t ws_size,
                              hipStream_t stream) {
    const float* x   = (const float*)d_in[0];
    const float* W1  = (const float*)d_in[1];
    const float* b1  = (const float*)d_in[2];
    const float* W2  = (const float*)d_in[3];
    const float* b2  = (const float*)d_in[4];
    const float* Wih = (const float*)d_in[5];
    const float* Whh = (const float*)d_in[6];
    const float* bih = (const float*)d_in[7];
    const float* bhh = (const float*)d_in[8];
    const float* Whr = (const float*)d_in[9];
    float* out = (float*)d_out;

    constexpr int Bb = 4, S = 4096;
    const int M = Bb * S; // 16384

    // workspace layout
    float* ws      = (float*)d_ws;
    float* beff    = ws;                         // 512
    float* gxbias  = beff + 512;                 // 256
    float* bf2     = gxbias + 256;               // 256
    float* Gx      = bf2 + 256;                  // 4096*256
    float* Gf      = Gx + S * 256;               // 4096*256
    float* Pp      = Gf + S * 256;               // 128*64
    float* Qq      = Pp + 8192;                  // 128*64
    float* h0      = Qq + 8192;                  // 4096
    float* h1      = h0 + S;                     // 4096
    __hip_bfloat16* xb     = (__hip_bfloat16*)(h1 + S);  // 16384*512
    __hip_bfloat16* W2b    = xb + (size_t)M * 512;       // 512*2048
    __hip_bfloat16* W1t    = W2b + 512 * 2048;           // 512*2048 (transposed)
    __hip_bfloat16* Wihb   = W1t + 512 * 2048;           // 256*512
    __hip_bfloat16* Weffb  = Wihb + 256 * 512;           // 512*512
    __hip_bfloat16* WeffTb = Weffb + 512 * 512;          // 512*512 (transposed)
    __hip_bfloat16* Wgb    = WeffTb + 512 * 512;         // 256*512

    float* fore = out + 2 * M;                   // (16384,512) region of d_out

    // L1: small weight conversions + transpose + gxbias
    convA_kernel<<<1409, 256, 0, stream>>>(
        W2, W1, Wih, bih, bhh, W2b, W1t, Wihb, gxbias);

    // L2: Weffb/WeffTb (front) || xb conversion stream + beff
    convB_kernel<<<2088, 256, 0, stream>>>(
        x, W2, b1, b2, W2b, W1t, xb, Weffb, WeffTb, beff);

    // L3: Wgb + bf2 + Gx
    wggx_kernel<<<145, 256, 0, stream>>>(
        Wihb, WeffTb, xb, Wih, beff, gxbias, Wgb, bf2, Gx);

    // K1 = scan-A0 + 1024 fore tiles (swizzled)
    fused_kernel<<<32 + 1024, 256, 0, stream>>>(
        0, 1, 0, 1024, 0,
        xb, Weffb, Wgb, beff, bf2, Gx, Gf, nullptr, gxbias, Whh, Whr,
        h0, h0, Pp, Qq, fore, out);

    // K2 = scan-B0 (-> h0) + 128 Gf tiles
    fused_kernel<<<32 + 128, 256, 0, stream>>>(
        1, 1, 0, 0, 128,
        xb, Weffb, Wgb, beff, bf2, Gx, Gf, nullptr, gxbias, Whh, Whr,
        h0, h0, Pp, Qq, fore, out);

    // K3 = scan-A1 (reads h0)
    fused_kernel<<<32, 256, 0, stream>>>(
        0, 0, 0, 0, 0,
        xb, Weffb, Wgb, beff, bf2, Gx, Gf, nullptr, gxbias, Whh, Whr,
        h0, h1, Pp, Qq, fore, out);

    // K4 = scan-B1 + fused forecast + output broadcasts
    fused_kernel<<<32, 256, 0, stream>>>(
        1, 0, 1, 0, 0,
        xb, Weffb, Wgb, beff, bf2, Gx, Gf, Gf, gxbias, Whh, Whr,
        h0, h1, Pp, Qq, fore, out);
}

// Round 23
// 140.715 us; speedup vs baseline: 1.0818x; 1.0818x over previous
//
#include <hip/hip_runtime.h>
#include <hip/hip_bf16.h>

// B=4, S=4096, D=512, FH=2048, H=64
// outputs: progress (B*S) ++ forecast (B*S) ++ fore (B*S*D), all f32
//
// Structure (7 launches):
//   L1 convA: W2b/W1t/Wihb bf16 + gxbias
//   L2 convB: Weff split-K partials (128 blocks, FRONT) || xb stream + beff
//   L3 wggx:  Weff-reduce -> Weffb/WeffTb (front) + bf2 + Gx tiles
//   K1: scan-A0 + 16 Wgb tiles (front) + 1024 fore tiles (XCD-swizzled)
//   K2: scan-B0 + 128 Gf tiles
//   K3: scan-A1
//   K4: scan-B1 with FUSED forecast cells + output broadcasts

#if __has_builtin(__builtin_amdgcn_exp2f)
__device__ __forceinline__ float EXP2(float x) { return __builtin_amdgcn_exp2f(x); }
#else
__device__ __forceinline__ float EXP2(float x) { return __expf(x * 0.6931471805599453f); }
#endif
#if __has_builtin(__builtin_amdgcn_rcpf)
__device__ __forceinline__ float RCPF(float x) { return __builtin_amdgcn_rcpf(x); }
#else
__device__ __forceinline__ float RCPF(float x) { return 1.0f / x; }
#endif

constexpr float L2E  = 1.4426950408889634f;
constexpr float L2E2 = 2.8853900817779268f;

__device__ __forceinline__ float sig_f(float x)  { return RCPF(1.0f + EXP2(-L2E * x)); }
__device__ __forceinline__ float tanh_f(float x) { return fmaf(-2.0f, RCPF(1.0f + EXP2(L2E2 * x)), 1.0f); }

template<int CTRL>
__device__ __forceinline__ float dppadd(float x) {
    return x + __int_as_float(__builtin_amdgcn_update_dpp(
        0, __float_as_int(x), CTRL, 0xf, 0xf, true));
}
__device__ __forceinline__ float dpp_sum64_lane63(float x) {
    x = dppadd<0x111>(x); x = dppadd<0x112>(x); x = dppadd<0x114>(x);
    x = dppadd<0x118>(x); x = dppadd<0x142>(x); x = dppadd<0x143>(x);
    return x;
}
__device__ __forceinline__ float readlane63(float x) {
    return __int_as_float(__builtin_amdgcn_readlane(__float_as_int(x), 63));
}
__device__ __forceinline__ float readlane_s(float x, int s) {
    return __int_as_float(__builtin_amdgcn_readlane(__float_as_int(x), s));
}

using bf16x8 = __attribute__((ext_vector_type(8))) __bf16;
using f32x4  = __attribute__((ext_vector_type(4))) float;

// ---------------------------------------------------------------------------
// MFMA 128x64 tile with LDS-staged B panel (64x512 bf16 = 64KB, XOR-swizzled).
// A: [M][lda] bf16 row-major (k-contiguous), VMEM double-buffered.
// B: [N][ldb] bf16 (B^T layout); staged per 512-k chunk into Bs.
// mfma_f32_16x16x32_bf16 layouts (verified round 11):
//   A/B-frag lane l: row/col = l&15, k = (l>>4)*8 + j
//   D        lane l: col = l&15, row = (l>>4)*4 + i
// ---------------------------------------------------------------------------
__device__ __forceinline__ void mfma_tile128_lds(
    const __hip_bfloat16* __restrict__ A, int lda,
    const __hip_bfloat16* __restrict__ B, int ldb,
    int K, int bm, int bn,
    const float* __restrict__ bias,                 // nullptr -> none
    float* __restrict__ Cf, int ldc,                // nullptr -> skip
    __hip_bfloat16* __restrict__ Cb,                // nullptr -> skip (ldc)
    __hip_bfloat16* __restrict__ Ct, int ldt,       // nullptr -> skip (transposed)
    __hip_bfloat16* __restrict__ Bs)                // shared, 64*512 elems
{
    const int tid  = threadIdx.x;
    const int w    = tid >> 6;
    const int lane = tid & 63;
    const int rc   = lane & 15;
    const int kg   = lane >> 4;
    const __hip_bfloat16* ap0 = A + (size_t)(bm + w * 16 + rc) * lda + kg * 8;
    const __hip_bfloat16* ap1 = ap0 + (size_t)64 * lda;

#define LD8(P) (*reinterpret_cast<const bf16x8*>(P))
    const f32x4 z{0.f, 0.f, 0.f, 0.f};
    f32x4 c00 = z, c01 = z, c02 = z, c03 = z;
    f32x4 c10 = z, c11 = z, c12 = z, c13 = z;

    for (int kb = 0; kb < K; kb += 512) {
        __syncthreads();
        #pragma unroll
        for (int i = 0; i < 16; ++i) {
            const int G = i * 256 + tid;
            const int row = G >> 6, kc = G & 63;
            const bf16x8 v = LD8(B + (size_t)(bn + row) * ldb + kb + kc * 8);
            *reinterpret_cast<bf16x8*>(Bs + row * 512 + ((kc ^ (row & 7)) << 3)) = v;
        }
        __syncthreads();

        bf16x8 a0 = LD8(ap0 + kb), a1 = LD8(ap1 + kb);
        #pragma unroll 4
        for (int s = 0; s < 16; ++s) {
            bf16x8 a0n = a0, a1n = a1;
            if (s < 15) {
                a0n = LD8(ap0 + kb + (s + 1) * 32);
                a1n = LD8(ap1 + kb + (s + 1) * 32);
            }
            bf16x8 bf[4];
            #pragma unroll
            for (int g = 0; g < 4; ++g) {
                const int row = g * 16 + rc;
                const int off = row * 512 + (((s * 4 + kg) ^ (row & 7)) << 3);
                bf[g] = *reinterpret_cast<const bf16x8*>(Bs + off);
            }
            c00 = __builtin_amdgcn_mfma_f32_16x16x32_bf16(a0, bf[0], c00, 0, 0, 0);
            c01 = __builtin_amdgcn_mfma_f32_16x16x32_bf16(a0, bf[1], c01, 0, 0, 0);
            c02 = __builtin_amdgcn_mfma_f32_16x16x32_bf16(a0, bf[2], c02, 0, 0, 0);
            c03 = __builtin_amdgcn_mfma_f32_16x16x32_bf16(a0, bf[3], c03, 0, 0, 0);
            c10 = __builtin_amdgcn_mfma_f32_16x16x32_bf16(a1, bf[0], c10, 0, 0, 0);
            c11 = __builtin_amdgcn_mfma_f32_16x16x32_bf16(a1, bf[1], c11, 0, 0, 0);
            c12 = __builtin_amdgcn_mfma_f32_16x16x32_bf16(a1, bf[2], c12, 0, 0, 0);
            c13 = __builtin_amdgcn_mfma_f32_16x16x32_bf16(a1, bf[3], c13, 0, 0, 0);
            a0 = a0n; a1 = a1n;
        }
    }
#undef LD8

    const int row0 = bm + w * 16 + kg * 4;
    const int colb = bn + rc;
#define EPI(ACC, HOFF, CT) {                                                  \
        const int col = colb + (CT) * 16;                                     \
        const float bb = bias ? bias[col] : 0.0f;                             \
        _Pragma("unroll")                                                     \
        for (int i = 0; i < 4; ++i) {                                         \
            const float v = (ACC)[i] + bb;                                    \
            const int row = row0 + (HOFF) + i;                                \
            if (Cf) Cf[(size_t)row * ldc + col] = v;                          \
            if (Cb) Cb[(size_t)row * ldc + col] = __float2bfloat16(v);        \
            if (Ct) Ct[(size_t)col * ldt + row] = __float2bfloat16(v);        \
        }}
    EPI(c00, 0, 0)  EPI(c01, 0, 1)  EPI(c02, 0, 2)  EPI(c03, 0, 3)
    EPI(c10, 64, 0) EPI(c11, 64, 1) EPI(c12, 64, 2) EPI(c13, 64, 3)
#undef EPI
}

// ---------------------------------------------------------------------------
// L1 convA: [0,1024) W2b | [1024,1280) W1t (LDS transpose) |
//           [1280,1408) Wihb | 1408 gxbias
// ---------------------------------------------------------------------------
__global__ __launch_bounds__(256) void convA_kernel(
    const float* __restrict__ W2, const float* __restrict__ W1,
    const float* __restrict__ Wih,
    const float* __restrict__ bih, const float* __restrict__ bhh,
    __hip_bfloat16* __restrict__ W2b, __hip_bfloat16* __restrict__ W1t,
    __hip_bfloat16* __restrict__ Wihb, float* __restrict__ gxbias)
{
    const int bid = blockIdx.x, tid = threadIdx.x;
#define CVT4(SRC, DST, BASE) {                                                \
        const size_t i = ((size_t)(BASE) * 256 + tid) * 4;                    \
        const float4 v = *reinterpret_cast<const float4*>((SRC) + i);         \
        __hip_bfloat16 o[4] = {__float2bfloat16(v.x), __float2bfloat16(v.y),  \
                               __float2bfloat16(v.z), __float2bfloat16(v.w)}; \
        *reinterpret_cast<ushort4*>((DST) + i) =                              \
            *reinterpret_cast<const ushort4*>(o); }
    if (bid < 1024) {
        CVT4(W2, W2b, bid)
    } else if (bid < 1280) {
        __shared__ float lds[64][65];
        const int b = bid - 1024;
        const int br = b >> 3, bc = b & 7;
        const int r0 = tid >> 4, c4 = (tid & 15) * 4;
        #pragma unroll
        for (int u = 0; u < 4; ++u) {
            const int row = r0 + u * 16;
            const float4 v = *reinterpret_cast<const float4*>(
                &W1[(size_t)(br * 64 + row) * 512 + bc * 64 + c4]);
            lds[row][c4 + 0] = v.x; lds[row][c4 + 1] = v.y;
            lds[row][c4 + 2] = v.z; lds[row][c4 + 3] = v.w;
        }
        __syncthreads();
        const int jj0 = tid >> 4, kk4 = (tid & 15) * 4;
        #pragma unroll
        for (int u = 0; u < 4; ++u) {
            const int jj = jj0 + u * 16;
            __hip_bfloat16 o[4] = {
                __float2bfloat16(lds[kk4 + 0][jj]), __float2bfloat16(lds[kk4 + 1][jj]),
                __float2bfloat16(lds[kk4 + 2][jj]), __float2bfloat16(lds[kk4 + 3][jj])};
            *reinterpret_cast<ushort4*>(
                &W1t[(size_t)(bc * 64 + jj) * 2048 + br * 64 + kk4]) =
                *reinterpret_cast<const ushort4*>(o);
        }
    } else if (bid < 1408) {
        CVT4(Wih, Wihb, bid - 1280)
    } else {
        gxbias[tid] = bih[tid] + bhh[tid];
    }
#undef CVT4
}

// ---------------------------------------------------------------------------
// L2 convB: [0,128) Weff split-K partial tiles (FRONT: tile=b>>2, ks=b&3);
//           [128,136) beff f32; [136,2184) xb conversion
// ---------------------------------------------------------------------------
__global__ __launch_bounds__(256) void convB_kernel(
    const float* __restrict__ x, const float* __restrict__ W2,
    const float* __restrict__ b1, const float* __restrict__ b2,
    const __hip_bfloat16* __restrict__ W2b, const __hip_bfloat16* __restrict__ W1t,
    __hip_bfloat16* __restrict__ xb, float* __restrict__ Wpart,
    float* __restrict__ beff)
{
    __shared__ __hip_bfloat16 Bs[64 * 512];
    const int bid = blockIdx.x, tid = threadIdx.x;
    if (bid < 128) {
        const int tile = bid >> 2, ks = bid & 3;
        const int bm = (tile >> 3) * 128, bn = (tile & 7) * 64;
        mfma_tile128_lds(W2b + ks * 512, 2048, W1t + ks * 512, 2048, 512,
                         bm, bn, nullptr,
                         Wpart + (size_t)ks * 512 * 512, 512,
                         nullptr, nullptr, 0, Bs);
    } else if (bid < 136) {
        const int w = tid >> 6, j = tid & 63;
        const int base = (bid - 128) * 64 + w * 16;
        for (int o = 0; o < 16; ++o) {
            const int i = base + o;
            float s = 0.0f;
            #pragma unroll
            for (int m = 0; m < 32; ++m)
                s = fmaf(W2[(size_t)i * 2048 + j + 64 * m], b1[j + 64 * m], s);
            s = dpp_sum64_lane63(s);
            if (j == 63) beff[i] = s + b2[i];
        }
    } else {
        const int b = bid - 136;                      // 2048 blocks, 1024 f4 each
        const float4* src = reinterpret_cast<const float4*>(x) + (size_t)b * 1024;
        ushort4* dst = reinterpret_cast<ushort4*>(xb) + (size_t)b * 1024;
        float4 v[4];
        #pragma unroll
        for (int u = 0; u < 4; ++u) v[u] = src[u * 256 + tid];
        #pragma unroll
        for (int u = 0; u < 4; ++u) {
            __hip_bfloat16 o[4] = {__float2bfloat16(v[u].x), __float2bfloat16(v[u].y),
                                   __float2bfloat16(v[u].z), __float2bfloat16(v[u].w)};
            dst[u * 256 + tid] = *reinterpret_cast<const ushort4*>(o);
        }
    }
}

// ---------------------------------------------------------------------------
// L3 wggx: [0,16) Weff reduce -> Weffb + WeffTb (FRONT); 16: bf2;
//          [17,145) Gx = xb@Wihb^T + gxbias
// ---------------------------------------------------------------------------
__global__ __launch_bounds__(256) void wggx_kernel(
    const float* __restrict__ Wpart,
    const __hip_bfloat16* __restrict__ Wihb, const __hip_bfloat16* __restrict__ xb,
    const float* __restrict__ Wih, const float* __restrict__ beff,
    const float* __restrict__ gxbias,
    __hip_bfloat16* __restrict__ Weffb, __hip_bfloat16* __restrict__ WeffTb,
    float* __restrict__ bf2, float* __restrict__ Gx)
{
    __shared__ __hip_bfloat16 Bs[64 * 512];
    const int bid = blockIdx.x;
    if (bid < 16) {
        // reduce 4 partials: 512*512 f32 -> bf16 (+ transposed scatter)
        const int tid = threadIdx.x;
        constexpr int NF4 = 512 * 512 / 4;       // 65536 f4 total, 4096/block
        for (int u = 0; u < 16; ++u) {
            const int g = (bid * 16 + u) * 256 + tid;   // f4 index
            if (g >= NF4) break;
            f32x4 s = *reinterpret_cast<const f32x4*>(Wpart + (size_t)g * 4);
            #pragma unroll
            for (int p = 1; p < 4; ++p) {
                const f32x4 v = *reinterpret_cast<const f32x4*>(
                    Wpart + (size_t)p * 512 * 512 + (size_t)g * 4);
                s[0] += v[0]; s[1] += v[1]; s[2] += v[2]; s[3] += v[3];
            }
            const int row = (g * 4) >> 9, col = (g * 4) & 511;
            __hip_bfloat16 o[4] = {__float2bfloat16(s[0]), __float2bfloat16(s[1]),
                                   __float2bfloat16(s[2]), __float2bfloat16(s[3])};
            *reinterpret_cast<ushort4*>(Weffb + (size_t)row * 512 + col) =
                *reinterpret_cast<const ushort4*>(o);
            #pragma unroll
            for (int e = 0; e < 4; ++e)
                WeffTb[(size_t)(col + e) * 512 + row] = o[e];
        }
    } else if (bid == 16) {
        const int w = threadIdx.x >> 6, j = threadIdx.x & 63;
        for (int o = 0; o < 64; ++o) {
            const int i = w * 64 + o;
            float s = 0.0f;
            #pragma unroll
            for (int m = 0; m < 8; ++m)
                s = fmaf(Wih[(size_t)i * 512 + j + 64 * m], beff[j + 64 * m], s);
            s = dpp_sum64_lane63(s);
            if (j == 63) bf2[i] = s;
        }
    } else {
        const int b = bid - 17;                       // 128 Gx tiles
        const int bm = (b >> 2) * 128, bn = (b & 3) * 64;
        mfma_tile128_lds(xb, 512, Wihb, 512, 512, bm, bn, gxbias,
                         Gx, 256, nullptr, nullptr, 0, Bs);
    }
}

// ---------------------------------------------------------------------------
// fused: [0,32) scan phase (128 chunk-waves, CH=32);
//        [32,32+wg_cnt) Wgb tiles (front); then fore_cnt fore tiles
//        (XCD-swizzled); then gf_cnt Gf tiles.
// phase B + last: forecast cell fused; outputs written directly.
// ---------------------------------------------------------------------------
__global__ __launch_bounds__(256) void fused_kernel(
    int phase, int first, int last,
    int wg_cnt, int fore_cnt, int gf_cnt,
    const __hip_bfloat16* __restrict__ xb, const __hip_bfloat16* __restrict__ Weffb,
    const __hip_bfloat16* __restrict__ WeffTb, const __hip_bfloat16* __restrict__ Wihb,
    __hip_bfloat16* __restrict__ Wgb, const __hip_bfloat16* __restrict__ Wgb_in,
    const float* __restrict__ beff, const float* __restrict__ bf2,
    const float* __restrict__ Gx, float* __restrict__ Gf,
    const float* __restrict__ Gf_in, const float* __restrict__ gxbias,
    const float* __restrict__ Whh, const float* __restrict__ Whr,
    const float* __restrict__ hprev, float* __restrict__ hnext,
    float* __restrict__ P, float* __restrict__ Q,
    float* __restrict__ fore, float* __restrict__ out)
{
    __shared__ __hip_bfloat16 Bs[64 * 512];
    constexpr int CH = 32;                          // steps per chunk
    constexpr int S = 4096, BS = 4 * 4096;

    if (blockIdx.x < 32) {
        const int chunk = blockIdx.x * 4 + (threadIdx.x >> 6);  // 0..127
        const int j = threadIdx.x & 63;
        const float wi = Whh[j], wf = Whh[64 + j];
        const float wg2 = Whh[128 + j], wo = Whh[192 + j];
        const float* ab = Gx + (size_t)chunk * CH * 256 + j;

        float hp = 0.0f;
        if (!first) {
            const int idx = chunk * CH - 1 + j;
            hp = (idx >= 0 && idx < S) ? hprev[idx] : 0.0f;
        }

        if (phase == 0) {
            float Pv = 1.0f, Qv = 0.0f;
            #pragma unroll 8
            for (int s = 0; s < CH; ++s) {
                const float hs = first ? 0.0f : readlane_s(hp, s);
                const float ai = ab[s * 256]       + wi  * hs;
                const float af = ab[s * 256 + 64]  + wf  * hs;
                const float ag = ab[s * 256 + 128] + wg2 * hs;
                const float si = sig_f(ai);
                const float sf = sig_f(af);
                const float tg = tanh_f(ag);
                Pv = sf * Pv;
                Qv = fmaf(sf, Qv, si * tg);
            }
            P[chunk * 64 + j] = Pv;
            Q[chunk * 64 + j] = Qv;
        } else {
            const float whr = Whr[j];
            float c = 0.0f;
            #pragma unroll 8
            for (int m = 0; m < chunk; ++m)
                c = fmaf(P[m * 64 + j], c, Q[m * 64 + j]);
            float vp = 0.0f, vpf = 0.0f;
            const float* gfp = Gf_in ? Gf_in + (size_t)chunk * CH * 256 + j : nullptr;
            const float bi0 = gxbias[j],        bi1 = gxbias[64 + j];
            const float bi2 = gxbias[128 + j],  bi3 = gxbias[192 + j];
            #pragma unroll 4
            for (int s = 0; s < CH; ++s) {
                const float hs = first ? 0.0f : readlane_s(hp, s);
                const float ai = ab[s * 256]       + wi  * hs;
                const float af = ab[s * 256 + 64]  + wf  * hs;
                const float ag = ab[s * 256 + 128] + wg2 * hs;
                const float ao = ab[s * 256 + 192] + wo  * hs;
                const float si = sig_f(ai);
                const float sf = sig_f(af);
                const float tg = tanh_f(ag);
                const float so = sig_f(ao);
                c = fmaf(sf, c, si * tg);
                const float tc = tanh_f(c);
                float hv = tc * (so * whr);
                hv = dpp_sum64_lane63(hv);
                const float hn = readlane63(hv);
                vp = (j == s) ? hn : vp;
                if (last) {
                    const float fi = gfp[s * 256]       + bi0 + wi  * hn;
                    const float ff = gfp[s * 256 + 64]  + bi1 + wf  * hn;
                    const float fg = gfp[s * 256 + 128] + bi2 + wg2 * hn;
                    const float fo = gfp[s * 256 + 192] + bi3 + wo  * hn;
                    const float cf = sig_f(ff) * c + sig_f(fi) * tanh_f(fg);
                    float hf = sig_f(fo) * tanh_f(cf) * whr;
                    hf = dpp_sum64_lane63(hf);
                    const float hfn = readlane63(hf);
                    vpf = (j == s) ? hfn : vpf;
                }
            }
            if (j < CH) {
                const int t = chunk * CH + j;
                if (last) {
                    #pragma unroll
                    for (int b = 0; b < 4; ++b) {
                        out[b * S + t]      = vp;
                        out[BS + b * S + t] = vpf;
                    }
                } else {
                    hnext[t] = vp;
                }
            }
        }
        return;
    }

    const int bt = blockIdx.x - 32;
    if (bt < wg_cnt) {                     // Wgb tiles FIRST (overlap fore)
        const int bm = (bt >> 3) * 128, bn = (bt & 7) * 64;
        mfma_tile128_lds(Wihb, 512, WeffTb, 512, 512, bm, bn, nullptr,
                         nullptr, 512, Wgb, nullptr, 0, Bs);
    } else if (bt < wg_cnt + fore_cnt) {   // fore: 1024 tiles, XCD-swizzled
        const int f = bt - wg_cnt;
        const int tile = (f & 7) * 128 + (f >> 3);    // stride-8 peers share panel
        const int bm = (tile >> 3) * 128, bn = (tile & 7) * 64;
        mfma_tile128_lds(xb, 512, Weffb, 512, 512, bm, bn, beff,
                         fore, 512, nullptr, nullptr, 0, Bs);
    } else if (bt < wg_cnt + fore_cnt + gf_cnt) {   // Gf: 128 tiles
        const int g = bt - wg_cnt - fore_cnt;
        const int bm = (g >> 2) * 128, bn = (g & 3) * 64;
        mfma_tile128_lds(xb, 512, Wgb_in, 512, 512, bm, bn, bf2,
                         Gf, 256, nullptr, nullptr, 0, Bs);
    }
}

extern "C" void kernel_launch(void* const* d_in, const int* in_sizes, int n_in,
                              void* d_out, int out_size, void* d_ws, size_t ws_size,
                              hipStream_t stream) {
    const float* x   = (const float*)d_in[0];
    const float* W1  = (const float*)d_in[1];
    const float* b1  = (const float*)d_in[2];
    const float* W2  = (const float*)d_in[3];
    const float* b2  = (const float*)d_in[4];
    const float* Wih = (const float*)d_in[5];
    const float* Whh = (const float*)d_in[6];
    const float* bih = (const float*)d_in[7];
    const float* bhh = (const float*)d_in[8];
    const float* Whr = (const float*)d_in[9];
    float* out = (float*)d_out;

    constexpr int Bb = 4, S = 4096;
    const int M = Bb * S; // 16384

    // workspace layout
    float* ws      = (float*)d_ws;
    float* beff    = ws;                         // 512
    float* gxbias  = beff + 512;                 // 256
    float* bf2     = gxbias + 256;               // 256
    float* Gx      = bf2 + 256;                  // 4096*256
    float* Gf      = Gx + S * 256;               // 4096*256
    float* Pp      = Gf + S * 256;               // 128*64
    float* Qq      = Pp + 8192;                  // 128*64
    float* h0      = Qq + 8192;                  // 4096
    float* h1      = h0 + S;                     // 4096
    float* Wpart   = h1 + S;                     // 4*512*512 f32
    __hip_bfloat16* xb     = (__hip_bfloat16*)(Wpart + 4 * 512 * 512);
    __hip_bfloat16* W2b    = xb + (size_t)M * 512;       // 512*2048
    __hip_bfloat16* W1t    = W2b + 512 * 2048;           // 512*2048 (transposed)
    __hip_bfloat16* Wihb   = W1t + 512 * 2048;           // 256*512
    __hip_bfloat16* Weffb  = Wihb + 256 * 512;           // 512*512
    __hip_bfloat16* WeffTb = Weffb + 512 * 512;          // 512*512 (transposed)
    __hip_bfloat16* Wgb    = WeffTb + 512 * 512;         // 256*512

    float* fore = out + 2 * M;                   // (16384,512) region of d_out

    // L1: small weight conversions + transpose + gxbias
    convA_kernel<<<1409, 256, 0, stream>>>(
        W2, W1, Wih, bih, bhh, W2b, W1t, Wihb, gxbias);

    // L2: Weff split-K partials (front) || xb conversion stream + beff
    convB_kernel<<<128 + 8 + 2048, 256, 0, stream>>>(
        x, W2, b1, b2, W2b, W1t, xb, Wpart, beff);

    // L3: Weff reduce (front) + bf2 + Gx
    wggx_kernel<<<145, 256, 0, stream>>>(
        Wpart, Wihb, xb, Wih, beff, gxbias, Weffb, WeffTb, bf2, Gx);

    // K1 = scan-A0 + 16 Wgb tiles (front) + 1024 fore tiles (swizzled)
    fused_kernel<<<32 + 16 + 1024, 256, 0, stream>>>(
        0, 1, 0, 16, 1024, 0,
        xb, Weffb, WeffTb, Wihb, Wgb, Wgb, beff, bf2,
        Gx, Gf, nullptr, gxbias, Whh, Whr,
        h0, h0, Pp, Qq, fore, out);

    // K2 = scan-B0 (-> h0) + 128 Gf tiles
    fused_kernel<<<32 + 128, 256, 0, stream>>>(
        1, 1, 0, 0, 0, 128,
        xb, Weffb, WeffTb, Wihb, Wgb, Wgb, beff, bf2,
        Gx, Gf, nullptr, gxbias, Whh, Whr,
        h0, h0, Pp, Qq, fore, out);

    // K3 = scan-A1 (reads h0)
    fused_kernel<<<32, 256, 0, stream>>>(
        0, 0, 0, 0, 0, 0,
        xb, Weffb, WeffTb, Wihb, Wgb, Wgb, beff, bf2,
        Gx, Gf, nullptr, gxbias, Whh, Whr,
        h0, h1, Pp, Qq, fore, out);

    // K4 = scan-B1 + fused forecast + output broadcasts
    fused_kernel<<<32, 256, 0, stream>>>(
        1, 0, 1, 0, 0, 0,
        xb, Weffb, WeffTb, Wihb, Wgb, Wgb, beff, bf2,
        Gx, Gf, Gf, gxbias, Whh, Whr,
        h0, h1, Pp, Qq, fore, out);
}

// Round 24
// 130.199 us; speedup vs baseline: 1.1692x; 1.0808x over previous
//
#include <hip/hip_runtime.h>
#include <hip/hip_bf16.h>

// B=4, S=4096, D=512, FH=2048, H=64
// outputs: progress (B*S) ++ forecast (B*S) ++ fore (B*S*D), all f32
//
// Structure (7 launches):
//   L1 convA: W2b/W1t/Wihb bf16 + gxbias + beff
//   L2 convB: Weff split-K partials (128 blocks, FRONT) || xb stream
//   L3 wggx:  Weff-reduce -> Weffb (front) + 128 Gx tiles
//   K1: scan-A0 + 1024 fore tiles (XCD-swizzled; rows<4096 also emit foreb)
//   K2: scan-B0 + 128 Gf tiles (Gf = foreb @ Wihb^T)
//   K3: scan-A1
//   K4: scan-B1 with FUSED forecast cells + output broadcasts

#if __has_builtin(__builtin_amdgcn_exp2f)
__device__ __forceinline__ float EXP2(float x) { return __builtin_amdgcn_exp2f(x); }
#else
__device__ __forceinline__ float EXP2(float x) { return __expf(x * 0.6931471805599453f); }
#endif
#if __has_builtin(__builtin_amdgcn_rcpf)
__device__ __forceinline__ float RCPF(float x) { return __builtin_amdgcn_rcpf(x); }
#else
__device__ __forceinline__ float RCPF(float x) { return 1.0f / x; }
#endif

constexpr float L2E  = 1.4426950408889634f;
constexpr float L2E2 = 2.8853900817779268f;

__device__ __forceinline__ float sig_f(float x)  { return RCPF(1.0f + EXP2(-L2E * x)); }
__device__ __forceinline__ float tanh_f(float x) { return fmaf(-2.0f, RCPF(1.0f + EXP2(L2E2 * x)), 1.0f); }

template<int CTRL>
__device__ __forceinline__ float dppadd(float x) {
    return x + __int_as_float(__builtin_amdgcn_update_dpp(
        0, __float_as_int(x), CTRL, 0xf, 0xf, true));
}
__device__ __forceinline__ float dpp_sum64_lane63(float x) {
    x = dppadd<0x111>(x); x = dppadd<0x112>(x); x = dppadd<0x114>(x);
    x = dppadd<0x118>(x); x = dppadd<0x142>(x); x = dppadd<0x143>(x);
    return x;
}
__device__ __forceinline__ float readlane63(float x) {
    return __int_as_float(__builtin_amdgcn_readlane(__float_as_int(x), 63));
}
__device__ __forceinline__ float readlane_s(float x, int s) {
    return __int_as_float(__builtin_amdgcn_readlane(__float_as_int(x), s));
}

using bf16x8 = __attribute__((ext_vector_type(8))) __bf16;
using f32x4  = __attribute__((ext_vector_type(4))) float;

// ---------------------------------------------------------------------------
// MFMA 128x64 tile with LDS-staged B panel (64x512 bf16 = 64KB, XOR-swizzled).
// A: [M][lda] bf16 row-major (k-contiguous), VMEM double-buffered.
// B: [N][ldb] bf16 (B^T layout); staged per 512-k chunk into Bs.
// mfma_f32_16x16x32_bf16 layouts (verified round 11):
//   A/B-frag lane l: row/col = l&15, k = (l>>4)*8 + j
//   D        lane l: col = l&15, row = (l>>4)*4 + i
// ---------------------------------------------------------------------------
__device__ __forceinline__ void mfma_tile128_lds(
    const __hip_bfloat16* __restrict__ A, int lda,
    const __hip_bfloat16* __restrict__ B, int ldb,
    int K, int bm, int bn,
    const float* __restrict__ bias,                 // nullptr -> none
    float* __restrict__ Cf, int ldc,                // nullptr -> skip
    __hip_bfloat16* __restrict__ Cb,                // nullptr -> skip (ldc)
    __hip_bfloat16* __restrict__ Bs)                // shared, 64*512 elems
{
    const int tid  = threadIdx.x;
    const int w    = tid >> 6;
    const int lane = tid & 63;
    const int rc   = lane & 15;
    const int kg   = lane >> 4;
    const __hip_bfloat16* ap0 = A + (size_t)(bm + w * 16 + rc) * lda + kg * 8;
    const __hip_bfloat16* ap1 = ap0 + (size_t)64 * lda;

#define LD8(P) (*reinterpret_cast<const bf16x8*>(P))
    const f32x4 z{0.f, 0.f, 0.f, 0.f};
    f32x4 c00 = z, c01 = z, c02 = z, c03 = z;
    f32x4 c10 = z, c11 = z, c12 = z, c13 = z;

    for (int kb = 0; kb < K; kb += 512) {
        __syncthreads();
        #pragma unroll
        for (int i = 0; i < 16; ++i) {
            const int G = i * 256 + tid;
            const int row = G >> 6, kc = G & 63;
            const bf16x8 v = LD8(B + (size_t)(bn + row) * ldb + kb + kc * 8);
            *reinterpret_cast<bf16x8*>(Bs + row * 512 + ((kc ^ (row & 7)) << 3)) = v;
        }
        __syncthreads();

        bf16x8 a0 = LD8(ap0 + kb), a1 = LD8(ap1 + kb);
        #pragma unroll 4
        for (int s = 0; s < 16; ++s) {
            bf16x8 a0n = a0, a1n = a1;
            if (s < 15) {
                a0n = LD8(ap0 + kb + (s + 1) * 32);
                a1n = LD8(ap1 + kb + (s + 1) * 32);
            }
            bf16x8 bf[4];
            #pragma unroll
            for (int g = 0; g < 4; ++g) {
                const int row = g * 16 + rc;
                const int off = row * 512 + (((s * 4 + kg) ^ (row & 7)) << 3);
                bf[g] = *reinterpret_cast<const bf16x8*>(Bs + off);
            }
            c00 = __builtin_amdgcn_mfma_f32_16x16x32_bf16(a0, bf[0], c00, 0, 0, 0);
            c01 = __builtin_amdgcn_mfma_f32_16x16x32_bf16(a0, bf[1], c01, 0, 0, 0);
            c02 = __builtin_amdgcn_mfma_f32_16x16x32_bf16(a0, bf[2], c02, 0, 0, 0);
            c03 = __builtin_amdgcn_mfma_f32_16x16x32_bf16(a0, bf[3], c03, 0, 0, 0);
            c10 = __builtin_amdgcn_mfma_f32_16x16x32_bf16(a1, bf[0], c10, 0, 0, 0);
            c11 = __builtin_amdgcn_mfma_f32_16x16x32_bf16(a1, bf[1], c11, 0, 0, 0);
            c12 = __builtin_amdgcn_mfma_f32_16x16x32_bf16(a1, bf[2], c12, 0, 0, 0);
            c13 = __builtin_amdgcn_mfma_f32_16x16x32_bf16(a1, bf[3], c13, 0, 0, 0);
            a0 = a0n; a1 = a1n;
        }
    }
#undef LD8

    const int row0 = bm + w * 16 + kg * 4;
    const int colb = bn + rc;
#define EPI(ACC, HOFF, CT) {                                                  \
        const int col = colb + (CT) * 16;                                     \
        const float bb = bias ? bias[col] : 0.0f;                             \
        _Pragma("unroll")                                                     \
        for (int i = 0; i < 4; ++i) {                                         \
            const float v = (ACC)[i] + bb;                                    \
            const int row = row0 + (HOFF) + i;                                \
            if (Cf) Cf[(size_t)row * ldc + col] = v;                          \
            if (Cb) Cb[(size_t)row * ldc + col] = __float2bfloat16(v);        \
        }}
    EPI(c00, 0, 0)  EPI(c01, 0, 1)  EPI(c02, 0, 2)  EPI(c03, 0, 3)
    EPI(c10, 64, 0) EPI(c11, 64, 1) EPI(c12, 64, 2) EPI(c13, 64, 3)
#undef EPI
}

// ---------------------------------------------------------------------------
// L1 convA: [0,1024) W2b | [1024,1280) W1t (LDS transpose) |
//           [1280,1408) Wihb | 1408 gxbias | [1409,1417) beff
// ---------------------------------------------------------------------------
__global__ __launch_bounds__(256) void convA_kernel(
    const float* __restrict__ W2, const float* __restrict__ W1,
    const float* __restrict__ Wih,
    const float* __restrict__ bih, const float* __restrict__ bhh,
    const float* __restrict__ b1, const float* __restrict__ b2,
    __hip_bfloat16* __restrict__ W2b, __hip_bfloat16* __restrict__ W1t,
    __hip_bfloat16* __restrict__ Wihb, float* __restrict__ gxbias,
    float* __restrict__ beff)
{
    const int bid = blockIdx.x, tid = threadIdx.x;
#define CVT4(SRC, DST, BASE) {                                                \
        const size_t i = ((size_t)(BASE) * 256 + tid) * 4;                    \
        const float4 v = *reinterpret_cast<const float4*>((SRC) + i);         \
        __hip_bfloat16 o[4] = {__float2bfloat16(v.x), __float2bfloat16(v.y),  \
                               __float2bfloat16(v.z), __float2bfloat16(v.w)}; \
        *reinterpret_cast<ushort4*>((DST) + i) =                              \
            *reinterpret_cast<const ushort4*>(o); }
    if (bid < 1024) {
        CVT4(W2, W2b, bid)
    } else if (bid < 1280) {
        __shared__ float lds[64][65];
        const int b = bid - 1024;
        const int br = b >> 3, bc = b & 7;
        const int r0 = tid >> 4, c4 = (tid & 15) * 4;
        #pragma unroll
        for (int u = 0; u < 4; ++u) {
            const int row = r0 + u * 16;
            const float4 v = *reinterpret_cast<const float4*>(
                &W1[(size_t)(br * 64 + row) * 512 + bc * 64 + c4]);
            lds[row][c4 + 0] = v.x; lds[row][c4 + 1] = v.y;
            lds[row][c4 + 2] = v.z; lds[row][c4 + 3] = v.w;
        }
        __syncthreads();
        const int jj0 = tid >> 4, kk4 = (tid & 15) * 4;
        #pragma unroll
        for (int u = 0; u < 4; ++u) {
            const int jj = jj0 + u * 16;
            __hip_bfloat16 o[4] = {
                __float2bfloat16(lds[kk4 + 0][jj]), __float2bfloat16(lds[kk4 + 1][jj]),
                __float2bfloat16(lds[kk4 + 2][jj]), __float2bfloat16(lds[kk4 + 3][jj])};
            *reinterpret_cast<ushort4*>(
                &W1t[(size_t)(bc * 64 + jj) * 2048 + br * 64 + kk4]) =
                *reinterpret_cast<const ushort4*>(o);
        }
    } else if (bid < 1408) {
        CVT4(Wih, Wihb, bid - 1280)
    } else if (bid == 1408) {
        gxbias[tid] = bih[tid] + bhh[tid];
    } else {
        const int w = tid >> 6, j = tid & 63;
        const int base = (bid - 1409) * 64 + w * 16;
        for (int o = 0; o < 16; ++o) {
            const int i = base + o;
            float s = 0.0f;
            #pragma unroll
            for (int m = 0; m < 32; ++m)
                s = fmaf(W2[(size_t)i * 2048 + j + 64 * m], b1[j + 64 * m], s);
            s = dpp_sum64_lane63(s);
            if (j == 63) beff[i] = s + b2[i];
        }
    }
#undef CVT4
}

// ---------------------------------------------------------------------------
// L2 convB: [0,128) Weff split-K partial tiles (FRONT: tile=b>>2, ks=b&3);
//           [128,2176) xb conversion (ILP-4 per thread)
// ---------------------------------------------------------------------------
__global__ __launch_bounds__(256) void convB_kernel(
    const float* __restrict__ x,
    const __hip_bfloat16* __restrict__ W2b, const __hip_bfloat16* __restrict__ W1t,
    __hip_bfloat16* __restrict__ xb, float* __restrict__ Wpart)
{
    __shared__ __hip_bfloat16 Bs[64 * 512];
    const int bid = blockIdx.x, tid = threadIdx.x;
    if (bid < 128) {
        const int tile = bid >> 2, ks = bid & 3;
        const int bm = (tile >> 3) * 128, bn = (tile & 7) * 64;
        mfma_tile128_lds(W2b + ks * 512, 2048, W1t + ks * 512, 2048, 512,
                         bm, bn, nullptr,
                         Wpart + (size_t)ks * 512 * 512, 512, nullptr, Bs);
    } else {
        const int b = bid - 128;                      // 2048 blocks, 1024 f4 each
        const float4* src = reinterpret_cast<const float4*>(x) + (size_t)b * 1024;
        ushort4* dst = reinterpret_cast<ushort4*>(xb) + (size_t)b * 1024;
        float4 v[4];
        #pragma unroll
        for (int u = 0; u < 4; ++u) v[u] = src[u * 256 + tid];
        #pragma unroll
        for (int u = 0; u < 4; ++u) {
            __hip_bfloat16 o[4] = {__float2bfloat16(v[u].x), __float2bfloat16(v[u].y),
                                   __float2bfloat16(v[u].z), __float2bfloat16(v[u].w)};
            dst[u * 256 + tid] = *reinterpret_cast<const ushort4*>(o);
        }
    }
}

// ---------------------------------------------------------------------------
// L3 wggx: [0,16) Weff reduce -> Weffb (FRONT); [16,144) Gx tiles
// ---------------------------------------------------------------------------
__global__ __launch_bounds__(256) void wggx_kernel(
    const float* __restrict__ Wpart,
    const __hip_bfloat16* __restrict__ Wihb, const __hip_bfloat16* __restrict__ xb,
    const float* __restrict__ gxbias,
    __hip_bfloat16* __restrict__ Weffb, float* __restrict__ Gx)
{
    __shared__ __hip_bfloat16 Bs[64 * 512];
    const int bid = blockIdx.x;
    if (bid < 16) {
        const int tid = threadIdx.x;
        for (int u = 0; u < 16; ++u) {
            const int g = (bid * 16 + u) * 256 + tid;   // f4 index, 65536 total
            f32x4 s = *reinterpret_cast<const f32x4*>(Wpart + (size_t)g * 4);
            #pragma unroll
            for (int p = 1; p < 4; ++p) {
                const f32x4 v = *reinterpret_cast<const f32x4*>(
                    Wpart + (size_t)p * 512 * 512 + (size_t)g * 4);
                s[0] += v[0]; s[1] += v[1]; s[2] += v[2]; s[3] += v[3];
            }
            __hip_bfloat16 o[4] = {__float2bfloat16(s[0]), __float2bfloat16(s[1]),
                                   __float2bfloat16(s[2]), __float2bfloat16(s[3])};
            *reinterpret_cast<ushort4*>(Weffb + (size_t)g * 4) =
                *reinterpret_cast<const ushort4*>(o);
        }
    } else {
        const int b = bid - 16;                       // 128 Gx tiles
        const int bm = (b >> 2) * 128, bn = (b & 3) * 64;
        mfma_tile128_lds(xb, 512, Wihb, 512, 512, bm, bn, gxbias,
                         Gx, 256, nullptr, Bs);
    }
}

// ---------------------------------------------------------------------------
// fused: [0,32) scan phase (128 chunk-waves, CH=32);
//        [32,32+fore_cnt) fore tiles (XCD-swizzled; rows<4096 emit foreb);
//        then gf_cnt Gf tiles (A = foreb).
// phase B + last: forecast cell fused; outputs written directly.
// ---------------------------------------------------------------------------
__global__ __launch_bounds__(256) void fused_kernel(
    int phase, int first, int last,
    int fore_cnt, int gf_cnt,
    const __hip_bfloat16* __restrict__ xb, const __hip_bfloat16* __restrict__ Weffb,
    const __hip_bfloat16* __restrict__ Wihb, const __hip_bfloat16* __restrict__ foreb_in,
    __hip_bfloat16* __restrict__ foreb_out,
    const float* __restrict__ beff,
    const float* __restrict__ Gx, float* __restrict__ Gf,
    const float* __restrict__ Gf_in, const float* __restrict__ gxbias,
    const float* __restrict__ Whh, const float* __restrict__ Whr,
    const float* __restrict__ hprev, float* __restrict__ hnext,
    float* __restrict__ P, float* __restrict__ Q,
    float* __restrict__ fore, float* __restrict__ out)
{
    __shared__ __hip_bfloat16 Bs[64 * 512];
    constexpr int CH = 32;                          // steps per chunk
    constexpr int S = 4096, BS = 4 * 4096;

    if (blockIdx.x < 32) {
        const int chunk = blockIdx.x * 4 + (threadIdx.x >> 6);  // 0..127
        const int j = threadIdx.x & 63;
        const float wi = Whh[j], wf = Whh[64 + j];
        const float wg2 = Whh[128 + j], wo = Whh[192 + j];
        const float* ab = Gx + (size_t)chunk * CH * 256 + j;

        float hp = 0.0f;
        if (!first) {
            const int idx = chunk * CH - 1 + j;
            hp = (idx >= 0 && idx < S) ? hprev[idx] : 0.0f;
        }

        if (phase == 0) {
            float Pv = 1.0f, Qv = 0.0f;
            #pragma unroll 8
            for (int s = 0; s < CH; ++s) {
                const float hs = first ? 0.0f : readlane_s(hp, s);
                const float ai = ab[s * 256]       + wi  * hs;
                const float af = ab[s * 256 + 64]  + wf  * hs;
                const float ag = ab[s * 256 + 128] + wg2 * hs;
                const float si = sig_f(ai);
                const float sf = sig_f(af);
                const float tg = tanh_f(ag);
                Pv = sf * Pv;
                Qv = fmaf(sf, Qv, si * tg);
            }
            P[chunk * 64 + j] = Pv;
            Q[chunk * 64 + j] = Qv;
        } else {
            const float whr = Whr[j];
            float c = 0.0f;
            #pragma unroll 8
            for (int m = 0; m < chunk; ++m)
                c = fmaf(P[m * 64 + j], c, Q[m * 64 + j]);
            float vp = 0.0f, vpf = 0.0f;
            const float* gfp = Gf_in ? Gf_in + (size_t)chunk * CH * 256 + j : nullptr;
            const float bi0 = gxbias[j],        bi1 = gxbias[64 + j];
            const float bi2 = gxbias[128 + j],  bi3 = gxbias[192 + j];
            #pragma unroll 4
            for (int s = 0; s < CH; ++s) {
                const float hs = first ? 0.0f : readlane_s(hp, s);
                const float ai = ab[s * 256]       + wi  * hs;
                const float af = ab[s * 256 + 64]  + wf  * hs;
                const float ag = ab[s * 256 + 128] + wg2 * hs;
                const float ao = ab[s * 256 + 192] + wo  * hs;
                const float si = sig_f(ai);
                const float sf = sig_f(af);
                const float tg = tanh_f(ag);
                const float so = sig_f(ao);
                c = fmaf(sf, c, si * tg);
                const float tc = tanh_f(c);
                float hv = tc * (so * whr);
                hv = dpp_sum64_lane63(hv);
                const float hn = readlane63(hv);
                vp = (j == s) ? hn : vp;
                if (last) {
                    const float fi = gfp[s * 256]       + bi0 + wi  * hn;
                    const float ff = gfp[s * 256 + 64]  + bi1 + wf  * hn;
                    const float fg = gfp[s * 256 + 128] + bi2 + wg2 * hn;
                    const float fo = gfp[s * 256 + 192] + bi3 + wo  * hn;
                    const float cf = sig_f(ff) * c + sig_f(fi) * tanh_f(fg);
                    float hf = sig_f(fo) * tanh_f(cf) * whr;
                    hf = dpp_sum64_lane63(hf);
                    const float hfn = readlane63(hf);
                    vpf = (j == s) ? hfn : vpf;
                }
            }
            if (j < CH) {
                const int t = chunk * CH + j;
                if (last) {
                    #pragma unroll
                    for (int b = 0; b < 4; ++b) {
                        out[b * S + t]      = vp;
                        out[BS + b * S + t] = vpf;
                    }
                } else {
                    hnext[t] = vp;
                }
            }
        }
        return;
    }

    const int bt = blockIdx.x - 32;
    if (bt < fore_cnt) {                   // fore: 1024 tiles, XCD-swizzled
        const int tile = (bt & 7) * 128 + (bt >> 3);   // stride-8 peers share panel
        const int bm = (tile >> 3) * 128, bn = (tile & 7) * 64;
        mfma_tile128_lds(xb, 512, Weffb, 512, 512, bm, bn, beff,
                         fore, 512, (bm < 4096) ? foreb_out : nullptr, Bs);
    } else if (bt < fore_cnt + gf_cnt) {   // Gf: 128 tiles, A = foreb
        const int g = bt - fore_cnt;
        const int bm = (g >> 2) * 128, bn = (g & 3) * 64;
        mfma_tile128_lds(foreb_in, 512, Wihb, 512, 512, bm, bn, nullptr,
                         Gf, 256, nullptr, Bs);
    }
}

extern "C" void kernel_launch(void* const* d_in, const int* in_sizes, int n_in,
                              void* d_out, int out_size, void* d_ws, size_t ws_size,
                              hipStream_t stream) {
    const float* x   = (const float*)d_in[0];
    const float* W1  = (const float*)d_in[1];
    const float* b1  = (const float*)d_in[2];
    const float* W2  = (const float*)d_in[3];
    const float* b2  = (const float*)d_in[4];
    const float* Wih = (const float*)d_in[5];
    const float* Whh = (const float*)d_in[6];
    const float* bih = (const float*)d_in[7];
    const float* bhh = (const float*)d_in[8];
    const float* Whr = (const float*)d_in[9];
    float* out = (float*)d_out;

    constexpr int Bb = 4, S = 4096;
    const int M = Bb * S; // 16384

    // workspace layout
    float* ws      = (float*)d_ws;
    float* beff    = ws;                         // 512
    float* gxbias  = beff + 512;                 // 256
    float* Gx      = gxbias + 256;               // 4096*256
    float* Gf      = Gx + S * 256;               // 4096*256
    float* Pp      = Gf + S * 256;               // 128*64
    float* Qq      = Pp + 8192;                  // 128*64
    float* h0      = Qq + 8192;                  // 4096
    float* h1      = h0 + S;                     // 4096
    float* Wpart   = h1 + S;                     // 4*512*512 f32
    __hip_bfloat16* xb     = (__hip_bfloat16*)(Wpart + 4 * 512 * 512);
    __hip_bfloat16* W2b    = xb + (size_t)M * 512;       // 512*2048
    __hip_bfloat16* W1t    = W2b + 512 * 2048;           // 512*2048 (transposed)
    __hip_bfloat16* Wihb   = W1t + 512 * 2048;           // 256*512
    __hip_bfloat16* Weffb  = Wihb + 256 * 512;           // 512*512
    __hip_bfloat16* foreb  = Weffb + 512 * 512;          // 4096*512

    float* fore = out + 2 * M;                   // (16384,512) region of d_out

    // L1: small weight conversions + transpose + gxbias + beff
    convA_kernel<<<1417, 256, 0, stream>>>(
        W2, W1, Wih, bih, bhh, b1, b2, W2b, W1t, Wihb, gxbias, beff);

    // L2: Weff split-K partials (front) || xb conversion stream
    convB_kernel<<<128 + 2048, 256, 0, stream>>>(
        x, W2b, W1t, xb, Wpart);

    // L3: Weff reduce (front) + Gx
    wggx_kernel<<<144, 256, 0, stream>>>(
        Wpart, Wihb, xb, gxbias, Weffb, Gx);

    // K1 = scan-A0 + 1024 fore tiles (swizzled; rows<4096 emit foreb)
    fused_kernel<<<32 + 1024, 256, 0, stream>>>(
        0, 1, 0, 1024, 0,
        xb, Weffb, Wihb, foreb, foreb, beff,
        Gx, Gf, nullptr, gxbias, Whh, Whr,
        h0, h0, Pp, Qq, fore, out);

    // K2 = scan-B0 (-> h0) + 128 Gf tiles (A = foreb)
    fused_kernel<<<32 + 128, 256, 0, stream>>>(
        1, 1, 0, 0, 128,
        xb, Weffb, Wihb, foreb, foreb, beff,
        Gx, Gf, nullptr, gxbias, Whh, Whr,
        h0, h0, Pp, Qq, fore, out);

    // K3 = scan-A1 (reads h0)
    fused_kernel<<<32, 256, 0, stream>>>(
        0, 0, 0, 0, 0,
        xb, Weffb, Wihb, foreb, foreb, beff,
        Gx, Gf, nullptr, gxbias, Whh, Whr,
        h0, h1, Pp, Qq, fore, out);

    // K4 = scan-B1 + fused forecast + output broadcasts
    fused_kernel<<<32, 256, 0, stream>>>(
        1, 0, 1, 0, 0,
        xb, Weffb, Wihb, foreb, foreb, beff,
        Gx, Gf, Gf, gxbias, Whh, Whr,
        h0, h1, Pp, Qq, fore, out);
}